// Round 1
// baseline (144.114 us; speedup 1.0000x reference)
//
#include <hip/hip_runtime.h>

// Maploss: per-row OHEM loss via histogram-based top-k selection.
// rows = 2 losses x 16 images, N = 512*512 per row.

#define THRESH 0.1f
constexpr int NPIX  = 512 * 512;   // 262144 elements per row
constexpr int NIMG  = 16;
constexpr int NROWS = 32;          // 2 losses * 16 images
constexpr int NBINS = 1024;        // value-histogram bins over v in [0,1)
constexpr int TPB   = 256;
constexpr int CPR   = 16;          // chunk-blocks per row
constexpr int CHUNK4 = NPIX / 4 / CPR;  // float4 per chunk = 4096 (16 per thread)

__global__ __launch_bounds__(TPB) void maploss_pass1(
    const float* __restrict__ gh, const float* __restrict__ gah,
    const float* __restrict__ pgh, const float* __restrict__ pgah,
    const float* __restrict__ mask,
    unsigned* __restrict__ g_cnt, float* __restrict__ g_sum,
    float* __restrict__ g_sumpos)
{
    const int chunk = blockIdx.x;
    const int img   = blockIdx.y;
    const int loss  = blockIdx.z;
    const size_t off = (size_t)img * NPIX;
    const float4* lb4 = (const float4*)((loss ? gah : gh) + off);
    const float4* pp4 = (const float4*)((loss ? pgah : pgh) + off);
    const float4* mm4 = (const float4*)(mask + off);
    const int row = loss * NIMG + img;

    __shared__ unsigned hc[NBINS];
    __shared__ float    hs[NBINS];
    for (int i = threadIdx.x; i < NBINS; i += TPB) { hc[i] = 0u; hs[i] = 0.f; }
    __syncthreads();

    float sum_pos = 0.f;
    const int base = chunk * CHUNK4;
    #pragma unroll
    for (int it = 0; it < CHUNK4 / TPB; ++it) {
        const int idx = base + it * TPB + threadIdx.x;
        float4 L = lb4[idx];
        float4 Pv = pp4[idx];
        float4 M = mm4[idx];
        float l[4] = {L.x, L.y, L.z, L.w};
        float p[4] = {Pv.x, Pv.y, Pv.z, Pv.w};
        float m[4] = {M.x, M.y, M.z, M.w};
        #pragma unroll
        for (int c = 0; c < 4; ++c) {
            float d = p[c] - l[c];
            float v = d * d * m[c];
            if (l[c] >= THRESH) {
                sum_pos += v;
            } else {
                int b = (int)(v * (float)NBINS);
                b = b < 0 ? 0 : (b > NBINS - 1 ? NBINS - 1 : b);
                atomicAdd(&hc[b], 1u);       // ds_add_u32
                atomicAdd(&hs[b], v);        // ds_add_f32
            }
        }
    }
    __syncthreads();

    // flush LDS histogram to per-row global histogram
    unsigned* gc = g_cnt + row * NBINS;
    float*    gs = g_sum + row * NBINS;
    for (int i = threadIdx.x; i < NBINS; i += TPB) {
        unsigned c = hc[i];
        if (c) {
            atomicAdd(&gc[i], c);
            unsafeAtomicAdd(&gs[i], hs[i]);  // native global_atomic_add_f32
        }
    }

    // block-reduce sum_pos (wave64 shuffle, then cross-wave)
    #pragma unroll
    for (int o = 32; o > 0; o >>= 1) sum_pos += __shfl_down(sum_pos, o, 64);
    __shared__ float wsum[TPB / 64];
    if ((threadIdx.x & 63) == 0) wsum[threadIdx.x >> 6] = sum_pos;
    __syncthreads();
    if (threadIdx.x == 0) {
        float s = 0.f;
        #pragma unroll
        for (int w = 0; w < TPB / 64; ++w) s += wsum[w];
        unsafeAtomicAdd(&g_sumpos[row], s);
    }
}

// One block per row: suffix-scan the histogram from the top, find the
// boundary bin for k = 3P (or 500 when P == 0), assemble per-row loss.
__global__ __launch_bounds__(TPB) void maploss_pass2(
    const unsigned* __restrict__ g_cnt, const float* __restrict__ g_sum,
    const float* __restrict__ g_sumpos, float* __restrict__ out)
{
    const int row = blockIdx.x;
    const unsigned* cnt = g_cnt + row * NBINS;
    const float*    bsm = g_sum + row * NBINS;
    const int tid = threadIdx.x;
    constexpr int BPT = NBINS / TPB;  // 4 bins per thread (contiguous)
    const int base = tid * BPT;

    unsigned c[BPT]; float s[BPT];
    #pragma unroll
    for (int i = 0; i < BPT; ++i) { c[i] = cnt[base + i]; s[i] = bsm[base + i]; }
    unsigned lc = 0; float ls = 0.f;
    #pragma unroll
    for (int i = 0; i < BPT; ++i) { lc += c[i]; ls += s[i]; }

    __shared__ unsigned sscan[TPB];
    __shared__ float    sred[TPB];
    sscan[tid] = lc;
    sred[tid]  = ls;
    __syncthreads();

    // total_sum = sum of all bin sums
    for (int o = TPB / 2; o > 0; o >>= 1) {
        if (tid < o) sred[tid] += sred[tid + o];
        __syncthreads();
    }
    const float total_sum = sred[0];
    __syncthreads();

    // inclusive suffix scan of counts: sscan[t] = sum_{t' >= t} lc[t']
    for (int o = 1; o < TPB; o <<= 1) {
        unsigned add = (tid + o < TPB) ? sscan[tid + o] : 0u;
        __syncthreads();
        sscan[tid] += add;
        __syncthreads();
    }
    const unsigned total_count = sscan[0];
    const unsigned E = sscan[tid] - lc;  // count in bins strictly above my range

    const int n_neg = (int)total_count;
    const int P = NPIX - n_neg;
    bool needSel; unsigned k;
    if (P > 0) { needSel = !(n_neg < 3 * P); k = 3u * (unsigned)P; }
    else       { needSel = true;             k = 500u; }

    __shared__ int   s_j;
    __shared__ float s_part;
    if (tid == 0) { s_j = NBINS; s_part = 0.f; }
    __syncthreads();

    if (needSel && E < k && E + lc >= k) {
        // boundary bin lies in my 4 bins; walk downward from my top bin
        unsigned cum = E;
        #pragma unroll
        for (int i = BPT - 1; i >= 0; --i) {
            unsigned cb = c[i];
            if (cum + cb >= k) {
                s_j = base + i;
                s_part = (float)(k - cum) * (s[i] / (float)cb);
                break;
            }
            cum += cb;
        }
    }
    __syncthreads();

    if (needSel) {
        const int j = s_j;
        float part = 0.f;
        #pragma unroll
        for (int i = 0; i < BPT; ++i) if (base + i > j) part += s[i];
        sred[tid] = part;
        __syncthreads();
        for (int o = TPB / 2; o > 0; o >>= 1) {
            if (tid < o) sred[tid] += sred[tid + o];
            __syncthreads();
        }
        if (tid == 0) {
            const float topk = sred[0] + s_part;
            float per_row;
            if (P > 0) {
                per_row = g_sumpos[row] / (float)P + topk / (float)k;
            } else {
                per_row = topk / 500.0f;
            }
            unsafeAtomicAdd(out, per_row * (1.0f / (float)NIMG));
        }
    } else {
        if (tid == 0) {
            // only reached when P > 0 and n_neg < 3P
            const float posi = g_sumpos[row] / (float)(P > 0 ? P : 1);
            const float nega = total_sum / (float)(n_neg > 0 ? n_neg : 1);
            unsafeAtomicAdd(out, (posi + nega) * (1.0f / (float)NIMG));
        }
    }
}

extern "C" void kernel_launch(void* const* d_in, const int* in_sizes, int n_in,
                              void* d_out, int out_size, void* d_ws, size_t ws_size,
                              hipStream_t stream)
{
    const float* gh   = (const float*)d_in[0];
    const float* gah  = (const float*)d_in[1];
    const float* pgh  = (const float*)d_in[2];
    const float* pgah = (const float*)d_in[3];
    const float* mask = (const float*)d_in[4];
    float* out = (float*)d_out;

    unsigned* g_cnt   = (unsigned*)d_ws;
    float*    g_sum   = (float*)((char*)d_ws + (size_t)NROWS * NBINS * 4);
    float*    g_sumpos= (float*)((char*)d_ws + (size_t)2 * NROWS * NBINS * 4);
    const size_t ws_used = (size_t)2 * NROWS * NBINS * 4 + NROWS * 4;

    hipMemsetAsync(d_ws, 0, ws_used, stream);
    hipMemsetAsync(d_out, 0, sizeof(float) * (size_t)out_size, stream);

    dim3 g1(CPR, NIMG, 2);
    maploss_pass1<<<g1, TPB, 0, stream>>>(gh, gah, pgh, pgah, mask,
                                          g_cnt, g_sum, g_sumpos);
    maploss_pass2<<<NROWS, TPB, 0, stream>>>(g_cnt, g_sum, g_sumpos, out);
}